// Round 1
// baseline (118.830 us; speedup 1.0000x reference)
//
#include <hip/hip_runtime.h>
#include <hip/hip_bf16.h>

#define TGT   64
#define SRCN  64
#define BATCH 32
#define HID   512
#define ATT   512

typedef __bf16 bf16_t;
typedef __bf16 bf16x8 __attribute__((ext_vector_type(8)));
typedef float  f32x4  __attribute__((ext_vector_type(4)));

__device__ __forceinline__ float fast_exp2(float x) {
#if __has_builtin(__builtin_amdgcn_exp2f)
  return __builtin_amdgcn_exp2f(x);
#else
  return exp2f(x);
#endif
}

__device__ __forceinline__ float fast_rcp(float x) {
#if __has_builtin(__builtin_amdgcn_rcpf)
  return __builtin_amdgcn_rcpf(x);
#else
  return 1.0f / x;
#endif
}

// tanh(x) = 1 - 2/(1 + exp2(2*log2(e)*x))
__device__ __forceinline__ float tanh_fast(float x) {
  float t = fast_exp2(x * 2.8853900817779268f);
  return 1.0f - 2.0f * fast_rcp(t + 1.0f);
}

#define MFMA(a, b, c) __builtin_amdgcn_mfma_f32_16x16x32_bf16((a), (b), (c), 0, 0, 0)

// C[m][n] = sum_k A[m][k] * B[k][n]; M=2048 (t*32+b rows), K=HID, N=ATT.
// bf16 hi/lo split MFMA for ~fp32 accuracy. Block tile 64x64, 4 waves in 2x2
// arrangement of 32x32 wave-tiles, K staged 32 at a time.
__global__ __launch_bounds__(256) void proj_gemm(
    const float* __restrict__ h_t, const float* __restrict__ srcp,
    const float* __restrict__ Wa, float* __restrict__ ws)
{
  const int z = blockIdx.z;
  const float* __restrict__ A = z ? srcp : h_t;
  const float* __restrict__ B = Wa + z * (HID * ATT);   // Wa_h rows 0..511, Wa_s rows 512..1023
  float* __restrict__ C = ws + (size_t)z * (TGT * BATCH * ATT);

  const int mbase = blockIdx.x * 64;
  const int nbase = blockIdx.y * 64;

  // +8 pad keeps 16B row alignment (40 bf16 = 80B) and breaks bank strides
  __shared__ bf16_t Ahi[64][40];
  __shared__ bf16_t Alo[64][40];
  __shared__ bf16_t Bhi[64][40];   // stored transposed: Bhi[n][k]
  __shared__ bf16_t Blo[64][40];

  const int tid  = threadIdx.x;
  const int lane = tid & 63;
  const int wv   = tid >> 6;
  const int wm   = (wv & 1) * 32;
  const int wn   = (wv >> 1) * 32;
  const int l15  = lane & 15;
  const int qd   = lane >> 4;

  f32x4 acc00 = {0.f, 0.f, 0.f, 0.f};
  f32x4 acc01 = acc00, acc10 = acc00, acc11 = acc00;

  const int am = tid >> 2;          // 0..63 (A tile row)
  const int ak = (tid & 3) * 8;     // 0,8,16,24
  const int bk = tid >> 3;          // 0..31 (B tile k-row)
  const int bn = (tid & 7) * 8;     // 0..56

  const float* Aptr = A + (size_t)(mbase + am) * HID + ak;
  const float* Bptr = B + (size_t)bk * ATT + nbase + bn;

  for (int kb = 0; kb < HID; kb += 32) {
    if (kb) __syncthreads();

    // stage A (row-major [m][k]) with hi/lo split
    float4 a0 = *(const float4*)(Aptr + kb);
    float4 a1 = *(const float4*)(Aptr + kb + 4);
    float av[8] = {a0.x, a0.y, a0.z, a0.w, a1.x, a1.y, a1.z, a1.w};
    bf16x8 ah, al;
#pragma unroll
    for (int j = 0; j < 8; ++j) {
      bf16_t hi = (bf16_t)av[j];
      ah[j] = hi;
      al[j] = (bf16_t)(av[j] - (float)hi);
    }
    *(bf16x8*)&Ahi[am][ak] = ah;
    *(bf16x8*)&Alo[am][ak] = al;

    // stage B transposed ([n][k]) so B-fragment reads are contiguous ds_read_b128
    float4 b0 = *(const float4*)(Bptr + (size_t)kb * ATT);
    float4 b1 = *(const float4*)(Bptr + (size_t)kb * ATT + 4);
    float bvv[8] = {b0.x, b0.y, b0.z, b0.w, b1.x, b1.y, b1.z, b1.w};
#pragma unroll
    for (int j = 0; j < 8; ++j) {
      bf16_t hi = (bf16_t)bvv[j];
      Bhi[bn + j][bk] = hi;
      Blo[bn + j][bk] = (bf16_t)(bvv[j] - (float)hi);
    }
    __syncthreads();

    // fragments: A[m=lane&15][k=quad*8+j], B[k=quad*8+j][n=lane&15] (via BT[n][k])
    bf16x8 ah0 = *(const bf16x8*)&Ahi[wm + l15][qd * 8];
    bf16x8 ah1 = *(const bf16x8*)&Ahi[wm + 16 + l15][qd * 8];
    bf16x8 al0 = *(const bf16x8*)&Alo[wm + l15][qd * 8];
    bf16x8 al1 = *(const bf16x8*)&Alo[wm + 16 + l15][qd * 8];
    bf16x8 bh0 = *(const bf16x8*)&Bhi[wn + l15][qd * 8];
    bf16x8 bh1 = *(const bf16x8*)&Bhi[wn + 16 + l15][qd * 8];
    bf16x8 bl0 = *(const bf16x8*)&Blo[wn + l15][qd * 8];
    bf16x8 bl1 = *(const bf16x8*)&Blo[wn + 16 + l15][qd * 8];

    acc00 = MFMA(ah0, bh0, acc00);
    acc01 = MFMA(ah0, bh1, acc01);
    acc10 = MFMA(ah1, bh0, acc10);
    acc11 = MFMA(ah1, bh1, acc11);
    acc00 = MFMA(ah0, bl0, acc00);
    acc01 = MFMA(ah0, bl1, acc01);
    acc10 = MFMA(ah1, bl0, acc10);
    acc11 = MFMA(ah1, bl1, acc11);
    acc00 = MFMA(al0, bh0, acc00);
    acc01 = MFMA(al0, bh1, acc01);
    acc10 = MFMA(al1, bh0, acc10);
    acc11 = MFMA(al1, bh1, acc11);
  }

  // C/D layout: row = quad*4 + reg, col = lane&15  [measured m89/m91]
#pragma unroll
  for (int r = 0; r < 4; ++r) {
    int row0 = mbase + wm + qd * 4 + r;
    int row1 = row0 + 16;
    int col0 = nbase + wn + l15;
    C[(size_t)row0 * ATT + col0]      = acc00[r];
    C[(size_t)row0 * ATT + col0 + 16] = acc01[r];
    C[(size_t)row1 * ATT + col0]      = acc10[r];
    C[(size_t)row1 * ATT + col0 + 16] = acc11[r];
  }
}

// Fused scores + softmax + context. One block per (4 targets, batch b).
// Wave w handles s = w*16..w*16+15 for scores; lane covers 8 a-elements.
__global__ __launch_bounds__(256) void attn_fused(
    const float* __restrict__ ws, const float* __restrict__ srcp,
    const float* __restrict__ Va, float* __restrict__ out)
{
  const float* __restrict__ h_part = ws;
  const float* __restrict__ s_part = ws + (size_t)TGT * BATCH * ATT;

  const int t0   = blockIdx.x * 4;
  const int b    = blockIdx.y;
  const int tid  = threadIdx.x;
  const int lane = tid & 63;
  const int wv   = tid >> 6;

  __shared__ float scoreLds[4][64];
  __shared__ float attnLds[4][64];

  const int abase = lane * 8;
  float va[8], H[4][8];
  *(float4*)&va[0] = *(const float4*)(Va + abase);
  *(float4*)&va[4] = *(const float4*)(Va + abase + 4);
#pragma unroll
  for (int t = 0; t < 4; ++t) {
    const float* hp = h_part + ((size_t)(t0 + t) * BATCH + b) * ATT + abase;
    *(float4*)&H[t][0] = *(const float4*)hp;
    *(float4*)&H[t][4] = *(const float4*)(hp + 4);
  }

  // ---- scores ----
#pragma unroll 2
  for (int i = 0; i < 16; ++i) {
    const int s = wv * 16 + i;
    const float* sp = s_part + ((size_t)s * BATCH + b) * ATT + abase;
    float4 s0 = *(const float4*)sp;
    float4 s1 = *(const float4*)(sp + 4);
    float sv[8] = {s0.x, s0.y, s0.z, s0.w, s1.x, s1.y, s1.z, s1.w};
    float p0 = 0.f, p1 = 0.f, p2 = 0.f, p3 = 0.f;
#pragma unroll
    for (int j = 0; j < 8; ++j) {
      float xv = sv[j];
      float vj = va[j];
      p0 = fmaf(tanh_fast(xv + H[0][j]), vj, p0);
      p1 = fmaf(tanh_fast(xv + H[1][j]), vj, p1);
      p2 = fmaf(tanh_fast(xv + H[2][j]), vj, p2);
      p3 = fmaf(tanh_fast(xv + H[3][j]), vj, p3);
    }
#pragma unroll
    for (int off = 32; off; off >>= 1) {
      p0 += __shfl_xor(p0, off);
      p1 += __shfl_xor(p1, off);
      p2 += __shfl_xor(p2, off);
      p3 += __shfl_xor(p3, off);
    }
    if (lane == 0) {
      scoreLds[0][s] = p0;
      scoreLds[1][s] = p1;
      scoreLds[2][s] = p2;
      scoreLds[3][s] = p3;
    }
  }
  __syncthreads();

  // ---- softmax over s (axis 0): wave w handles t = w, lane = s ----
  {
    float sc = scoreLds[wv][lane];
    float m = sc;
#pragma unroll
    for (int off = 32; off; off >>= 1) m = fmaxf(m, __shfl_xor(m, off));
    float e = fast_exp2((sc - m) * 1.4426950408889634f);
    float ssum = e;
#pragma unroll
    for (int off = 32; off; off >>= 1) ssum += __shfl_xor(ssum, off);
    attnLds[wv][lane] = e * fast_rcp(ssum);
  }
  __syncthreads();

  // ---- context: out[t,b,h] = sum_s attn[s][t] * src[s,b,h] ----
  const int hp2 = tid * 2;
  float2 c0 = {0.f, 0.f}, c1 = c0, c2 = c0, c3 = c0;
  const float* sb = srcp + (size_t)b * HID + hp2;
#pragma unroll 4
  for (int s = 0; s < SRCN; ++s) {
    float2 sv = *(const float2*)(sb + (size_t)s * BATCH * HID);
    float a0 = attnLds[0][s], a1 = attnLds[1][s];
    float a2 = attnLds[2][s], a3 = attnLds[3][s];
    c0.x = fmaf(a0, sv.x, c0.x); c0.y = fmaf(a0, sv.y, c0.y);
    c1.x = fmaf(a1, sv.x, c1.x); c1.y = fmaf(a1, sv.y, c1.y);
    c2.x = fmaf(a2, sv.x, c2.x); c2.y = fmaf(a2, sv.y, c2.y);
    c3.x = fmaf(a3, sv.x, c3.x); c3.y = fmaf(a3, sv.y, c3.y);
  }
  *(float2*)(out + ((size_t)(t0 + 0) * BATCH + b) * HID + hp2) = c0;
  *(float2*)(out + ((size_t)(t0 + 1) * BATCH + b) * HID + hp2) = c1;
  *(float2*)(out + ((size_t)(t0 + 2) * BATCH + b) * HID + hp2) = c2;
  *(float2*)(out + ((size_t)(t0 + 3) * BATCH + b) * HID + hp2) = c3;
}

extern "C" void kernel_launch(void* const* d_in, const int* in_sizes, int n_in,
                              void* d_out, int out_size, void* d_ws, size_t ws_size,
                              hipStream_t stream) {
  const float* h_t = (const float*)d_in[0];   // (64,32,512)
  const float* src = (const float*)d_in[1];   // (64,32,512)
  const float* Wa  = (const float*)d_in[2];   // (1024,512)
  const float* Va  = (const float*)d_in[3];   // (512,)
  float* out = (float*)d_out;                 // (64,32,512)
  float* ws  = (float*)d_ws;                  // needs 2 * 2048*512 * 4B = 8 MB

  // h_part (z=0) and s_part (z=1) projections via bf16 hi/lo MFMA
  proj_gemm<<<dim3(32, 8, 2), 256, 0, stream>>>(h_t, src, Wa, ws);
  // fused tanh-scores + softmax + context
  attn_fused<<<dim3(16, 32), 256, 0, stream>>>(ws, src, Va, out);
}